// Round 1
// baseline (5583.676 us; speedup 1.0000x reference)
//
#include <hip/hip_runtime.h>
#include <stdint.h>

// Problem constants
#define C_ 10
#define Q_ 1000
#define R_ 1024
#define N_ 512
#define S_ 10000
#define CQ 10000
#define KP 10240   // K padded to multiple of 256 for GEMM tiling

// Workspace layout (bytes). Total ~42 MB.
#define OFF_DT    0ULL           // bf16 Dt [1024][KP]            20,971,520
#define OFF_GP    20971520ULL    // f32 GP  [4][1024][1024]       16,777,216
#define OFF_SIG   37748736ULL    // f32 sigma/L [1024][1024]       4,194,304
#define OFF_MU    41943040ULL    // f32 mu-sums [10][1024]            40,960
#define OFF_E     41984000ULL    // f32 E [522]                        2,088
#define OFF_CLS   41986088ULL    // f32 cls accum
#define OFF_AMAX  41986096ULL    // u64 amax [10]
#define OFF_KC    41986176ULL    // int kc [10]
#define OFF_GOFF  41986216ULL    // int goff [10]
#define OFF_GIDX  41986256ULL    // int gidx [512]

typedef __attribute__((ext_vector_type(8))) short bf16x8;
typedef __attribute__((ext_vector_type(4))) float f32x4;

// ---------------- prep: histogram, grouping, zero accumulators ----------------
__global__ void k_prep(const int* __restrict__ labels, int* kc, int* goff, int* gidx,
                       float* mu, float* cls_accum, unsigned long long* amax) {
  __shared__ int cnt[C_];
  __shared__ int off[C_];
  int t = threadIdx.x;
  if (t < C_) cnt[t] = 0;
  __syncthreads();
  for (int i = t; i < N_; i += 256) atomicAdd(&cnt[labels[i]], 1);
  __syncthreads();
  if (t == 0) {
    int acc = 0;
    for (int c = 0; c < C_; c++) { off[c] = acc; goff[c] = acc; kc[c] = cnt[c]; acc += cnt[c]; }
    for (int i = 0; i < N_; i++) { int c = labels[i]; gidx[off[c]++] = i; }
    *cls_accum = 0.f;
  }
  if (t < C_) amax[t] = 0ULL;
  for (int i = t; i < C_ * R_; i += 256) mu[i] = 0.f;
}

// ---------------- eps: per-class argmax of ||eps||^2 (reads 410 MB) ----------------
__global__ __launch_bounds__(256) void k_epsmax(const float* __restrict__ eps,
                                                unsigned long long* amax) {
  int c = blockIdx.y;
  int chunk = blockIdx.x;                 // 0..126
  int t = threadIdx.x, lane = t & 63, w = t >> 6;
  const int per = 79;                     // 127*79 = 10033 >= 10000
  int s0 = chunk * per;
  int s1 = min(s0 + per, S_);
  float bv = -1.f; int bs = 0;
  for (int s = s0 + w; s < s1; s += 4) {
    const float4* p = (const float4*)(eps + ((size_t)c * S_ + s) * R_);
    float acc = 0.f;
#pragma unroll
    for (int m = 0; m < 4; m++) {
      float4 v = p[lane + 64 * m];
      acc += v.x * v.x + v.y * v.y + v.z * v.z + v.w * v.w;
    }
#pragma unroll
    for (int d = 32; d > 0; d >>= 1) acc += __shfl_xor(acc, d);
    if (acc > bv) { bv = acc; bs = s; }
  }
  __shared__ float svv[4]; __shared__ int ssi[4];
  if (lane == 0) { svv[w] = bv; ssi[w] = bs; }
  __syncthreads();
  if (t == 0) {
    float m = svv[0]; int mi = ssi[0];
    for (int i = 1; i < 4; i++) if (svv[i] > m) { m = svv[i]; mi = ssi[i]; }
    if (m >= 0.f) {
      unsigned long long pk = ((unsigned long long)__float_as_uint(m) << 32) | (unsigned)mi;
      atomicMax(amax + c, pk);
    }
  }
}

// ---------------- scores, focal loss, row energies ----------------
__global__ void k_scores(const float* __restrict__ box, const int* __restrict__ labels,
                         const float* __restrict__ Wp, const float* __restrict__ bp,
                         const float* __restrict__ we, float* __restrict__ E,
                         float* cls_accum) {
  int i = blockIdx.x;
  int lane = threadIdx.x;   // 64 threads
  float s[C_];
#pragma unroll
  for (int k = 0; k < C_; k++) s[k] = 0.f;
  const float* bi = box + (size_t)i * R_;
  for (int r = lane; r < R_; r += 64) {
    float x = bi[r];
#pragma unroll
    for (int k = 0; k < C_; k++) s[k] += x * Wp[k * R_ + r];
  }
#pragma unroll
  for (int k = 0; k < C_; k++) {
#pragma unroll
    for (int d = 32; d > 0; d >>= 1) s[k] += __shfl_xor(s[k], d);
  }
  if (lane == 0) {
    int lab = labels[i];
    float sc[C_]; float m = -1e30f;
#pragma unroll
    for (int k = 0; k < C_; k++) { sc[k] = s[k] + bp[k]; m = fmaxf(m, sc[k]); }
    float fsum = 0.f, esum = 0.f;
#pragma unroll
    for (int k = 0; k < C_; k++) {
      float x = sc[k];
      float tt = (k == lab) ? 1.f : 0.f;
      float p = 1.f / (1.f + expf(-x));
      float ce = fmaxf(x, 0.f) - x * tt + log1pf(expf(-fabsf(x)));
      float pt = p * tt + (1.f - p) * (1.f - tt);
      float at = 0.25f * tt + 0.75f * (1.f - tt);
      float om = 1.f - pt;
      fsum += at * ce * om * om;
      esum += expf(x - m) * fmaxf(we[k], 0.f);
    }
    atomicAdd(cls_accum, fsum);
    E[i] = m + logf(esum);
  }
}

// ---------------- build bf16 Dt^T [R][KP] (updated-queue rows) + mu sums ----------------
__global__ __launch_bounds__(256) void k_convert(const float* __restrict__ idd,
                                                 const float* __restrict__ box,
                                                 const int* __restrict__ kc,
                                                 const int* __restrict__ goff,
                                                 const int* __restrict__ gidx,
                                                 uint16_t* __restrict__ Dt,
                                                 float* __restrict__ mu) {
  __shared__ const float* rowsrc[64];
  __shared__ int rcls[64];
  __shared__ float T[64][65];
  int bk = blockIdx.x;   // 0..159 (k tile)
  int br = blockIdx.y;   // 0..15  (r tile)
  int t = threadIdx.x;
  int t0 = bk * 64, r0 = br * 64;
  if (t < 64) {
    int row = t0 + t;
    const float* src = nullptr; int c = -1;
    if (row < CQ) {
      c = row / Q_;
      int q = row - c * Q_;
      int k = kc[c];
      if (q < Q_ - k) src = idd + (size_t)(c * Q_ + q + k) * R_;
      else            src = box + (size_t)gidx[goff[c] + (q - (Q_ - k))] * R_;
    }
    rowsrc[t] = src; rcls[t] = c;
  }
  __syncthreads();
  int rr = t & 63, k4 = t >> 6;
#pragma unroll
  for (int it = 0; it < 16; it++) {
    int kk = k4 + it * 4;
    const float* src = rowsrc[kk];
    T[kk][rr] = src ? src[r0 + rr] : 0.f;
  }
  __syncthreads();
  if (t < 64 && t0 < CQ) {
    int c0 = rcls[0];
    float s0 = 0.f, s1 = 0.f; int c1 = -1;
    for (int kk = 0; kk < 64; kk++) {
      int c = rcls[kk]; float v = T[kk][t];
      if (c == c0) s0 += v; else if (c >= 0) { c1 = c; s1 += v; }
    }
    atomicAdd(&mu[c0 * R_ + r0 + t], s0);
    if (c1 >= 0) atomicAdd(&mu[c1 * R_ + r0 + t], s1);
  }
  int kk2 = t & 63, r4 = t >> 6;
#pragma unroll
  for (int it = 0; it < 16; it++) {
    int rr2 = r4 + it * 4;
    float v = T[kk2][rr2];
    uint32_t u = __float_as_uint(v);
    uint32_t b = (u + 0x7fffu + ((u >> 16) & 1u)) >> 16;   // RNE f32->bf16
    Dt[(size_t)(r0 + rr2) * KP + t0 + kk2] = (uint16_t)b;
  }
}

// ---------------- G = Dt * Dt^T via bf16 MFMA, split-K=4 ----------------
__global__ __launch_bounds__(256) void k_gemm(const uint16_t* __restrict__ Dt,
                                              float* __restrict__ GP) {
  __shared__ uint16_t lA[128 * 64];
  __shared__ uint16_t lB[128 * 64];
  int bi = blockIdx.x, bj = blockIdx.y, bz = blockIdx.z;
  int t = threadIdx.x;
  int lane = t & 63, w = t >> 6;
  int i0 = bi * 128, j0 = bj * 128;
  int lane16 = lane & 15, quad = lane >> 4;
  int wm = w >> 1, wn = w & 1;
  int srow = t >> 1, shalf = t & 1;
  const uint4* DU = (const uint4*)Dt;    // row pitch KP/8 = 1280 uint4
  int kz0 = bz * 320;                    // 2560 bf16 per split
  f32x4 acc[4][4];
#pragma unroll
  for (int a = 0; a < 4; a++)
#pragma unroll
    for (int b = 0; b < 4; b++) acc[a][b] = (f32x4){0.f, 0.f, 0.f, 0.f};

  for (int kt8 = 0; kt8 < 320; kt8 += 8) {   // 64 bf16 per LDS tile
    const uint4* pa = DU + (size_t)(i0 + srow) * 1280 + kz0 + kt8 + shalf * 4;
    const uint4* pb = DU + (size_t)(j0 + srow) * 1280 + kz0 + kt8 + shalf * 4;
    uint4* la4 = (uint4*)(lA + srow * 64 + shalf * 32);
    uint4* lb4 = (uint4*)(lB + srow * 64 + shalf * 32);
#pragma unroll
    for (int u = 0; u < 4; u++) la4[u] = pa[u];
#pragma unroll
    for (int u = 0; u < 4; u++) lb4[u] = pb[u];
    __syncthreads();
#pragma unroll
    for (int ch = 0; ch < 2; ch++) {
      bf16x8 af[4], bfr[4];
#pragma unroll
      for (int mi = 0; mi < 4; mi++)
        af[mi] = *(const bf16x8*)(lA + (wm * 64 + mi * 16 + lane16) * 64 + ch * 32 + quad * 8);
#pragma unroll
      for (int ni = 0; ni < 4; ni++)
        bfr[ni] = *(const bf16x8*)(lB + (wn * 64 + ni * 16 + lane16) * 64 + ch * 32 + quad * 8);
#pragma unroll
      for (int mi = 0; mi < 4; mi++)
#pragma unroll
        for (int ni = 0; ni < 4; ni++)
          acc[mi][ni] = __builtin_amdgcn_mfma_f32_16x16x32_bf16(af[mi], bfr[ni], acc[mi][ni], 0, 0, 0);
    }
    __syncthreads();
  }
  float* gp = GP + (size_t)bz * 1048576;
#pragma unroll
  for (int mi = 0; mi < 4; mi++)
#pragma unroll
    for (int ni = 0; ni < 4; ni++) {
      int col = j0 + wn * 64 + ni * 16 + lane16;
      int rowb = i0 + wm * 64 + mi * 16 + quad * 4;
#pragma unroll
      for (int r = 0; r < 4; r++)
        gp[(size_t)(rowb + r) * 1024 + col] = acc[mi][ni][r];
    }
}

// ---------------- sigma = G/CQ - Q/CQ * sum_c mu mu^T + eps*I ----------------
__global__ void k_reduce(const float* __restrict__ GP, const float* __restrict__ mu,
                         float* __restrict__ sig) {
  int idx = blockIdx.x * 256 + threadIdx.x;   // 0..1048575
  int i = idx >> 10, j = idx & 1023;
  float g = GP[idx] + GP[idx + 1048576] + GP[idx + 2097152] + GP[idx + 3145728];
  float mm = 0.f;
#pragma unroll
  for (int c = 0; c < C_; c++) mm += mu[c * R_ + i] * mu[c * R_ + j];
  sig[idx] = g * 1e-4f - mm * 1e-7f + ((i == j) ? 1e-4f : 0.f);
}

// ---------------- Cholesky: NB=128 blocked right-looking (in-place, lower) ----------------
#define SIDX(i, j) ((i) * 128 + (((i) + (j)) & 127))
__global__ __launch_bounds__(256) void k_chol_diag(float* __restrict__ sig, int p) {
  __shared__ float a[16384];   // 64 KB, diagonal-swizzled
  int t = threadIdx.x;
  int base = p * 128;
  for (int idx = t; idx < 16384; idx += 256) {
    int i = idx >> 7, j = idx & 127;
    if (j <= i) a[SIDX(i, j)] = sig[(size_t)(base + i) * 1024 + base + j];
  }
  __syncthreads();
  int ti = t >> 4, tk = t & 15;
  for (int j = 0; j < 128; j++) {
    float piv = a[SIDX(j, j)];
    float invp = 1.0f / piv;
    float ci[8], ck[8];
#pragma unroll
    for (int m = 0; m < 8; m++) ci[m] = a[SIDX(ti * 8 + m, j)];
#pragma unroll
    for (int n = 0; n < 8; n++) ck[n] = a[SIDX(tk * 8 + n, j)];
#pragma unroll
    for (int m = 0; m < 8; m++) {
      int i = ti * 8 + m;
#pragma unroll
      for (int n = 0; n < 8; n++) {
        int k = tk * 8 + n;
        if (k <= i && i > j && k > j)
          a[SIDX(i, k)] -= ci[m] * ck[n] * invp;
      }
    }
    __syncthreads();
  }
  for (int idx = t; idx < 16384; idx += 256) {
    int i = idx >> 7, j = idx & 127;
    if (j <= i) {
      float piv = a[SIDX(j, j)];
      float v = a[SIDX(i, j)];
      sig[(size_t)(base + i) * 1024 + base + j] = (i == j) ? sqrtf(piv) : v / sqrtf(piv);
    }
  }
}

__global__ __launch_bounds__(256) void k_chol_trsm(float* __restrict__ sig, int p) {
  __shared__ float XT[128][64];
  __shared__ float invd[128];
  int t = threadIdx.x;
  int base = p * 128;
  int row0 = base + 128 + blockIdx.x * 64;
  int r = t & 63, g = t >> 6;
  if (t < 128) invd[t] = 1.0f / sig[(size_t)(base + t) * 1024 + base + t];
  for (int j = g; j < 128; j += 4)
    XT[j][r] = sig[(size_t)(row0 + r) * 1024 + base + j];
  __syncthreads();
  for (int j = 0; j < 128; j++) {
    if (g == 0) XT[j][r] *= invd[j];
    __syncthreads();
    float xj = XT[j][r];
    for (int k = j + 1 + g; k < 128; k += 4) {
      float l = sig[(size_t)(base + k) * 1024 + base + j];
      XT[k][r] -= xj * l;
    }
    __syncthreads();
  }
  for (int j = g; j < 128; j += 4)
    sig[(size_t)(row0 + r) * 1024 + base + j] = XT[j][r];
}

__global__ __launch_bounds__(256) void k_chol_syrk(float* __restrict__ sig, int p) {
  __shared__ float PA[64][65], PB[64][65];
  int t = threadIdx.x;
  int tb = p * 128 + 128;
  int bx = blockIdx.x;
  int I = 0;
  while ((I + 1) * (I + 2) / 2 <= bx) I++;
  int K = bx - I * (I + 1) / 2;
  int gi = tb + I * 64, gk = tb + K * 64;
  int a4 = t >> 4, b4 = t & 15;
  float acc[4][4];
#pragma unroll
  for (int m = 0; m < 4; m++)
#pragma unroll
    for (int n = 0; n < 4; n++) acc[m][n] = 0.f;
  for (int ch = 0; ch < 2; ch++) {
    int cb = p * 128 + ch * 64;
    for (int idx = t; idx < 4096; idx += 256) {
      int rr = idx >> 6, cc = idx & 63;
      PA[rr][cc] = sig[(size_t)(gi + rr) * 1024 + cb + cc];
      PB[rr][cc] = sig[(size_t)(gk + rr) * 1024 + cb + cc];
    }
    __syncthreads();
    for (int j = 0; j < 64; j++) {
      float pa[4], pb[4];
#pragma unroll
      for (int m = 0; m < 4; m++) pa[m] = PA[a4 * 4 + m][j];
#pragma unroll
      for (int n = 0; n < 4; n++) pb[n] = PB[b4 * 4 + n][j];
#pragma unroll
      for (int m = 0; m < 4; m++)
#pragma unroll
        for (int n = 0; n < 4; n++) acc[m][n] += pa[m] * pb[n];
    }
    __syncthreads();
  }
#pragma unroll
  for (int m = 0; m < 4; m++)
#pragma unroll
    for (int n = 0; n < 4; n++)
      sig[(size_t)(gi + a4 * 4 + m) * 1024 + gk + b4 * 4 + n] -= acc[m][n];
}

// ---------------- VOS: gather eps_sel, vos = mu + eps_sel L^T, scores_vos, energy ----------------
__global__ __launch_bounds__(256) void k_vos(const float* __restrict__ eps,
                                             const float* __restrict__ L,
                                             const float* __restrict__ mu,
                                             const float* __restrict__ Wp,
                                             const float* __restrict__ bp,
                                             const float* __restrict__ we,
                                             const unsigned long long* __restrict__ amax,
                                             float* __restrict__ E) {
  __shared__ float es[1024];
  __shared__ float ys[1024];
  __shared__ float sv[16];
  int c = blockIdx.x, t = threadIdx.x;
  int idx = (int)(amax[c] & 0xffffffffULL);
  for (int i = t; i < 1024; i += 256) es[i] = eps[((size_t)c * S_ + idx) * R_ + i];
  __syncthreads();
  for (int rep = 0; rep < 4; rep++) {
    int i = rep * 256 + t;
    const float* Lr = L + (size_t)i * 1024;
    float a0 = 0.f, a1 = 0.f, a2 = 0.f, a3 = 0.f;
    int j = 0;
    for (; j + 3 <= i; j += 4) {
      a0 += es[j] * Lr[j];
      a1 += es[j + 1] * Lr[j + 1];
      a2 += es[j + 2] * Lr[j + 2];
      a3 += es[j + 3] * Lr[j + 3];
    }
    for (; j <= i; j++) a0 += es[j] * Lr[j];
    ys[i] = mu[c * R_ + i] * 1e-3f + ((a0 + a1) + (a2 + a3));
  }
  __syncthreads();
  if (t < C_) {
    float acc = bp[t];
    const float* Wr = Wp + (size_t)t * R_;
    for (int j = 0; j < 1024; j++) acc += ys[j] * Wr[j];
    sv[t] = acc;
  }
  __syncthreads();
  if (t == 0) {
    float m = -1e30f;
    for (int k = 0; k < C_; k++) m = fmaxf(m, sv[k]);
    float sum = 0.f;
    for (int k = 0; k < C_; k++) sum += expf(sv[k] - m) * fmaxf(we[k], 0.f);
    E[N_ + c] = m + logf(sum);
  }
}

// ---------------- tail MLP + BCE + outputs ----------------
__global__ __launch_bounds__(256) void k_dist(const float* __restrict__ E,
                                              const float* __restrict__ W1,
                                              const float* __restrict__ b1,
                                              const float* __restrict__ W2,
                                              const float* __restrict__ b2,
                                              const float* __restrict__ cls_accum,
                                              float* __restrict__ out) {
  __shared__ float sW1[512], sb1[512], sW2[512];
  __shared__ float red[4];
  int t = threadIdx.x;
  for (int i = t; i < 512; i += 256) { sW1[i] = W1[i]; sb1[i] = b1[i]; sW2[i] = W2[i]; }
  __syncthreads();
  float sum = 0.f;
  for (int i = t; i < N_ + C_; i += 256) {
    float e = E[i];
    float acc = b2[0];
    for (int j = 0; j < 512; j++) acc += sW2[j] * fmaxf(e * sW1[j] + sb1[j], 0.f);
    float y = (i < N_) ? 1.f : 0.f;
    float l = fmaxf(acc, 0.f) - acc * y + log1pf(expf(-fabsf(acc)));
    sum += l;
  }
#pragma unroll
  for (int d = 32; d > 0; d >>= 1) sum += __shfl_xor(sum, d);
  if ((t & 63) == 0) red[t >> 6] = sum;
  __syncthreads();
  if (t == 0) {
    out[1] = 0.1f * (red[0] + red[1] + red[2] + red[3]) / 522.f;
    out[0] = *cls_accum / 512.f;
  }
}

extern "C" void kernel_launch(void* const* d_in, const int* in_sizes, int n_in,
                              void* d_out, int out_size, void* d_ws, size_t ws_size,
                              hipStream_t stream) {
  (void)in_sizes; (void)n_in; (void)out_size; (void)ws_size;
  const float* box  = (const float*)d_in[0];
  const int*   lab  = (const int*)d_in[1];
  const float* idd  = (const float*)d_in[2];
  const float* Wp   = (const float*)d_in[4];
  const float* bp   = (const float*)d_in[5];
  const float* we   = (const float*)d_in[6];
  const float* W1   = (const float*)d_in[7];
  const float* b1   = (const float*)d_in[8];
  const float* W2   = (const float*)d_in[9];
  const float* b2   = (const float*)d_in[10];
  const float* eps  = (const float*)d_in[11];
  float* out = (float*)d_out;

  char* ws = (char*)d_ws;
  uint16_t* Dt = (uint16_t*)(ws + OFF_DT);
  float* GP    = (float*)(ws + OFF_GP);
  float* sig   = (float*)(ws + OFF_SIG);
  float* mu    = (float*)(ws + OFF_MU);
  float* E     = (float*)(ws + OFF_E);
  float* clsa  = (float*)(ws + OFF_CLS);
  unsigned long long* amax = (unsigned long long*)(ws + OFF_AMAX);
  int* kc   = (int*)(ws + OFF_KC);
  int* goff = (int*)(ws + OFF_GOFF);
  int* gidx = (int*)(ws + OFF_GIDX);

  hipLaunchKernelGGL(k_prep, dim3(1), dim3(256), 0, stream, lab, kc, goff, gidx, mu, clsa, amax);
  hipLaunchKernelGGL(k_epsmax, dim3(127, C_), dim3(256), 0, stream, eps, amax);
  hipLaunchKernelGGL(k_scores, dim3(N_), dim3(64), 0, stream, box, lab, Wp, bp, we, E, clsa);
  hipLaunchKernelGGL(k_convert, dim3(160, 16), dim3(256), 0, stream, idd, box, kc, goff, gidx, Dt, mu);
  hipLaunchKernelGGL(k_gemm, dim3(8, 8, 4), dim3(256), 0, stream, Dt, GP);
  hipLaunchKernelGGL(k_reduce, dim3(4096), dim3(256), 0, stream, GP, mu, sig);
  for (int p = 0; p < 8; p++) {
    hipLaunchKernelGGL(k_chol_diag, dim3(1), dim3(256), 0, stream, sig, p);
    int rows = 1024 - 128 * (p + 1);
    if (rows > 0) {
      int nb = rows / 64;
      hipLaunchKernelGGL(k_chol_trsm, dim3(nb), dim3(256), 0, stream, sig, p);
      hipLaunchKernelGGL(k_chol_syrk, dim3(nb * (nb + 1) / 2), dim3(256), 0, stream, sig, p);
    }
  }
  hipLaunchKernelGGL(k_vos, dim3(C_), dim3(256), 0, stream, eps, sig, mu, Wp, bp, we, amax, E);
  hipLaunchKernelGGL(k_dist, dim3(1), dim3(256), 0, stream, E, W1, b1, W2, b2, clsa, out);
}

// Round 2
// 2016.309 us; speedup vs baseline: 2.7693x; 2.7693x over previous
//
#include <hip/hip_runtime.h>
#include <stdint.h>

// Problem constants
#define C_ 10
#define Q_ 1000
#define R_ 1024
#define N_ 512
#define S_ 10000
#define CQ 10000
#define KP 10240   // K padded to multiple of 256 for GEMM tiling

// Workspace layout (bytes). Total ~42 MB.
#define OFF_DT    0ULL           // bf16 Dt [1024][KP]            20,971,520
#define OFF_GP    20971520ULL    // f32 GP  [4][1024][1024]       16,777,216
#define OFF_SIG   37748736ULL    // f32 sigma/L [1024][1024]       4,194,304
#define OFF_MU    41943040ULL    // f32 mu-sums [10][1024]            40,960
#define OFF_E     41984000ULL    // f32 E [522]                        2,088
#define OFF_CLS   41986088ULL    // f32 cls accum
#define OFF_AMAX  41986096ULL    // u64 amax [10]
#define OFF_KC    41986176ULL    // int kc [10]
#define OFF_GOFF  41986216ULL    // int goff [10]
#define OFF_GIDX  41986256ULL    // int gidx [512]

typedef __attribute__((ext_vector_type(8))) short bf16x8;
typedef __attribute__((ext_vector_type(4))) float f32x4;

// ---------------- prep: histogram, grouping, zero accumulators ----------------
__global__ void k_prep(const int* __restrict__ labels, int* kc, int* goff, int* gidx,
                       float* mu, float* cls_accum, unsigned long long* amax) {
  __shared__ int cnt[C_];
  __shared__ int off[C_];
  int t = threadIdx.x;
  if (t < C_) cnt[t] = 0;
  __syncthreads();
  for (int i = t; i < N_; i += 256) atomicAdd(&cnt[labels[i]], 1);
  __syncthreads();
  if (t == 0) {
    int acc = 0;
    for (int c = 0; c < C_; c++) { off[c] = acc; goff[c] = acc; kc[c] = cnt[c]; acc += cnt[c]; }
    for (int i = 0; i < N_; i++) { int c = labels[i]; gidx[off[c]++] = i; }
    *cls_accum = 0.f;
  }
  if (t < C_) amax[t] = 0ULL;
  for (int i = t; i < C_ * R_; i += 256) mu[i] = 0.f;
}

// ---------------- eps: per-class argmax of ||eps||^2 (reads 410 MB) ----------------
__global__ __launch_bounds__(256) void k_epsmax(const float* __restrict__ eps,
                                                unsigned long long* amax) {
  int c = blockIdx.y;
  int chunk = blockIdx.x;                 // 0..126
  int t = threadIdx.x, lane = t & 63, w = t >> 6;
  const int per = 79;                     // 127*79 = 10033 >= 10000
  int s0 = chunk * per;
  int s1 = min(s0 + per, S_);
  float bv = -1.f; int bs = 0;
  for (int s = s0 + w; s < s1; s += 4) {
    const float4* p = (const float4*)(eps + ((size_t)c * S_ + s) * R_);
    float acc = 0.f;
#pragma unroll
    for (int m = 0; m < 4; m++) {
      float4 v = p[lane + 64 * m];
      acc += v.x * v.x + v.y * v.y + v.z * v.z + v.w * v.w;
    }
#pragma unroll
    for (int d = 32; d > 0; d >>= 1) acc += __shfl_xor(acc, d);
    if (acc > bv) { bv = acc; bs = s; }
  }
  __shared__ float svv[4]; __shared__ int ssi[4];
  if (lane == 0) { svv[w] = bv; ssi[w] = bs; }
  __syncthreads();
  if (t == 0) {
    float m = svv[0]; int mi = ssi[0];
    for (int i = 1; i < 4; i++) if (svv[i] > m) { m = svv[i]; mi = ssi[i]; }
    if (m >= 0.f) {
      unsigned long long pk = ((unsigned long long)__float_as_uint(m) << 32) | (unsigned)mi;
      atomicMax(amax + c, pk);
    }
  }
}

// ---------------- scores, focal loss, row energies ----------------
__global__ void k_scores(const float* __restrict__ box, const int* __restrict__ labels,
                         const float* __restrict__ Wp, const float* __restrict__ bp,
                         const float* __restrict__ we, float* __restrict__ E,
                         float* cls_accum) {
  int i = blockIdx.x;
  int lane = threadIdx.x;   // 64 threads
  float s[C_];
#pragma unroll
  for (int k = 0; k < C_; k++) s[k] = 0.f;
  const float* bi = box + (size_t)i * R_;
  for (int r = lane; r < R_; r += 64) {
    float x = bi[r];
#pragma unroll
    for (int k = 0; k < C_; k++) s[k] += x * Wp[k * R_ + r];
  }
#pragma unroll
  for (int k = 0; k < C_; k++) {
#pragma unroll
    for (int d = 32; d > 0; d >>= 1) s[k] += __shfl_xor(s[k], d);
  }
  if (lane == 0) {
    int lab = labels[i];
    float sc[C_]; float m = -1e30f;
#pragma unroll
    for (int k = 0; k < C_; k++) { sc[k] = s[k] + bp[k]; m = fmaxf(m, sc[k]); }
    float fsum = 0.f, esum = 0.f;
#pragma unroll
    for (int k = 0; k < C_; k++) {
      float x = sc[k];
      float tt = (k == lab) ? 1.f : 0.f;
      float p = 1.f / (1.f + expf(-x));
      float ce = fmaxf(x, 0.f) - x * tt + log1pf(expf(-fabsf(x)));
      float pt = p * tt + (1.f - p) * (1.f - tt);
      float at = 0.25f * tt + 0.75f * (1.f - tt);
      float om = 1.f - pt;
      fsum += at * ce * om * om;
      esum += expf(x - m) * fmaxf(we[k], 0.f);
    }
    atomicAdd(cls_accum, fsum);
    E[i] = m + logf(esum);
  }
}

// ---------------- build bf16 Dt^T [R][KP] (updated-queue rows) + mu sums ----------------
__global__ __launch_bounds__(256) void k_convert(const float* __restrict__ idd,
                                                 const float* __restrict__ box,
                                                 const int* __restrict__ kc,
                                                 const int* __restrict__ goff,
                                                 const int* __restrict__ gidx,
                                                 uint16_t* __restrict__ Dt,
                                                 float* __restrict__ mu) {
  __shared__ const float* rowsrc[64];
  __shared__ int rcls[64];
  __shared__ float T[64][65];
  int bk = blockIdx.x;   // 0..159 (k tile)
  int br = blockIdx.y;   // 0..15  (r tile)
  int t = threadIdx.x;
  int t0 = bk * 64, r0 = br * 64;
  if (t < 64) {
    int row = t0 + t;
    const float* src = nullptr; int c = -1;
    if (row < CQ) {
      c = row / Q_;
      int q = row - c * Q_;
      int k = kc[c];
      if (q < Q_ - k) src = idd + (size_t)(c * Q_ + q + k) * R_;
      else            src = box + (size_t)gidx[goff[c] + (q - (Q_ - k))] * R_;
    }
    rowsrc[t] = src; rcls[t] = c;
  }
  __syncthreads();
  int rr = t & 63, k4 = t >> 6;
#pragma unroll
  for (int it = 0; it < 16; it++) {
    int kk = k4 + it * 4;
    const float* src = rowsrc[kk];
    T[kk][rr] = src ? src[r0 + rr] : 0.f;
  }
  __syncthreads();
  if (t < 64 && t0 < CQ) {
    int c0 = rcls[0];
    float s0 = 0.f, s1 = 0.f; int c1 = -1;
    for (int kk = 0; kk < 64; kk++) {
      int c = rcls[kk]; float v = T[kk][t];
      if (c == c0) s0 += v; else if (c >= 0) { c1 = c; s1 += v; }
    }
    atomicAdd(&mu[c0 * R_ + r0 + t], s0);
    if (c1 >= 0) atomicAdd(&mu[c1 * R_ + r0 + t], s1);
  }
  int kk2 = t & 63, r4 = t >> 6;
#pragma unroll
  for (int it = 0; it < 16; it++) {
    int rr2 = r4 + it * 4;
    float v = T[kk2][rr2];
    uint32_t u = __float_as_uint(v);
    uint32_t b = (u + 0x7fffu + ((u >> 16) & 1u)) >> 16;   // RNE f32->bf16
    Dt[(size_t)(r0 + rr2) * KP + t0 + kk2] = (uint16_t)b;
  }
}

// ---------------- G = Dt * Dt^T via bf16 MFMA, split-K=4 ----------------
__global__ __launch_bounds__(256) void k_gemm(const uint16_t* __restrict__ Dt,
                                              float* __restrict__ GP) {
  __shared__ uint16_t lA[128 * 64];
  __shared__ uint16_t lB[128 * 64];
  int bi = blockIdx.x, bj = blockIdx.y, bz = blockIdx.z;
  int t = threadIdx.x;
  int lane = t & 63, w = t >> 6;
  int i0 = bi * 128, j0 = bj * 128;
  int lane16 = lane & 15, quad = lane >> 4;
  int wm = w >> 1, wn = w & 1;
  int srow = t >> 1, shalf = t & 1;
  const uint4* DU = (const uint4*)Dt;    // row pitch KP/8 = 1280 uint4
  int kz0 = bz * 320;                    // 2560 bf16 per split
  f32x4 acc[4][4];
#pragma unroll
  for (int a = 0; a < 4; a++)
#pragma unroll
    for (int b = 0; b < 4; b++) acc[a][b] = (f32x4){0.f, 0.f, 0.f, 0.f};

  for (int kt8 = 0; kt8 < 320; kt8 += 8) {   // 64 bf16 per LDS tile
    const uint4* pa = DU + (size_t)(i0 + srow) * 1280 + kz0 + kt8 + shalf * 4;
    const uint4* pb = DU + (size_t)(j0 + srow) * 1280 + kz0 + kt8 + shalf * 4;
    uint4* la4 = (uint4*)(lA + srow * 64 + shalf * 32);
    uint4* lb4 = (uint4*)(lB + srow * 64 + shalf * 32);
#pragma unroll
    for (int u = 0; u < 4; u++) la4[u] = pa[u];
#pragma unroll
    for (int u = 0; u < 4; u++) lb4[u] = pb[u];
    __syncthreads();
#pragma unroll
    for (int ch = 0; ch < 2; ch++) {
      bf16x8 af[4], bfr[4];
#pragma unroll
      for (int mi = 0; mi < 4; mi++)
        af[mi] = *(const bf16x8*)(lA + (wm * 64 + mi * 16 + lane16) * 64 + ch * 32 + quad * 8);
#pragma unroll
      for (int ni = 0; ni < 4; ni++)
        bfr[ni] = *(const bf16x8*)(lB + (wn * 64 + ni * 16 + lane16) * 64 + ch * 32 + quad * 8);
#pragma unroll
      for (int mi = 0; mi < 4; mi++)
#pragma unroll
        for (int ni = 0; ni < 4; ni++)
          acc[mi][ni] = __builtin_amdgcn_mfma_f32_16x16x32_bf16(af[mi], bfr[ni], acc[mi][ni], 0, 0, 0);
    }
    __syncthreads();
  }
  float* gp = GP + (size_t)bz * 1048576;
#pragma unroll
  for (int mi = 0; mi < 4; mi++)
#pragma unroll
    for (int ni = 0; ni < 4; ni++) {
      int col = j0 + wn * 64 + ni * 16 + lane16;
      int rowb = i0 + wm * 64 + mi * 16 + quad * 4;
#pragma unroll
      for (int r = 0; r < 4; r++)
        gp[(size_t)(rowb + r) * 1024 + col] = acc[mi][ni][r];
    }
}

// ---------------- sigma = G/CQ - Q/CQ * sum_c mu mu^T + eps*I ----------------
__global__ void k_reduce(const float* __restrict__ GP, const float* __restrict__ mu,
                         float* __restrict__ sig) {
  int idx = blockIdx.x * 256 + threadIdx.x;   // 0..1048575
  int i = idx >> 10, j = idx & 1023;
  float g = GP[idx] + GP[idx + 1048576] + GP[idx + 2097152] + GP[idx + 3145728];
  float mm = 0.f;
#pragma unroll
  for (int c = 0; c < C_; c++) mm += mu[c * R_ + i] * mu[c * R_ + j];
  sig[idx] = g * 1e-4f - mm * 1e-7f + ((i == j) ? 1e-4f : 0.f);
}

// ---------------- Cholesky: NB=128 blocked right-looking (in-place, lower) ----------------
// diag: panel-blocked (PW=16). Phase A: single wave, panel in registers, shfl broadcasts.
// Phase B: rank-16 trailing update, 4x4 register tiles. LDS = exactly 64 KB via
// rotation swizzle a[i][(j+i)&127] (row & column accesses both conflict-free).
#define AIDX(i, j) (((i) << 7) + (((j) + (i)) & 127))
__global__ __launch_bounds__(256) void k_chol_diag(float* __restrict__ sig, int p) {
  __shared__ float a[16384];   // 64 KB
  int t = threadIdx.x;
  int base = p * 128;
  int lane = t & 63, wv = t >> 6;
  for (int idx = t; idx < 16384; idx += 256) {
    int i = idx >> 7, j = idx & 127;
    a[AIDX(i, j)] = sig[(size_t)(base + i) * 1024 + base + j];
  }
  __syncthreads();
  for (int panel = 0; panel < 8; panel++) {
    int j0 = panel * 16;
    if (wv == 0) {
      // ---- Phase A: factor 128x16 panel in registers (wave 0 only) ----
      float pa0[16], pa1[16];
#pragma unroll
      for (int jj = 0; jj < 16; jj++) {
        pa0[jj] = a[AIDX(lane, j0 + jj)];
        pa1[jj] = a[AIDX(lane + 64, j0 + jj)];
      }
#pragma unroll
      for (int jj = 0; jj < 16; jj++) {
        int j = j0 + jj;
        float pv0 = __shfl(pa0[jj], j & 63);
        float pv1 = __shfl(pa1[jj], j & 63);
        float pv = (j < 64) ? pv0 : pv1;
        float rsq = rsqrtf(pv);
        rsq = rsq * (1.5f - 0.5f * pv * rsq * rsq);   // Newton refine
        pa0[jj] *= rsq;
        pa1[jj] *= rsq;
#pragma unroll
        for (int kk = jj + 1; kk < 16; kk++) {
          int k = j0 + kk;
          float av0 = __shfl(pa0[jj], k & 63);
          float av1 = __shfl(pa1[jj], k & 63);
          float akj = (k < 64) ? av0 : av1;
          pa0[kk] -= pa0[jj] * akj;
          pa1[kk] -= pa1[jj] * akj;
        }
      }
#pragma unroll
      for (int jj = 0; jj < 16; jj++) {
        a[AIDX(lane, j0 + jj)] = pa0[jj];
        a[AIDX(lane + 64, j0 + jj)] = pa1[jj];
      }
    }
    __syncthreads();
    // ---- Phase B: trailing rank-16 update ----
    int m0 = j0 + 16;
    int M = 128 - m0;
    if (M > 0) {
      int T4 = M >> 2;
      int ntiles = T4 * (T4 + 1) / 2;
      for (int tb = t; tb < ntiles; tb += 256) {
        int I = (int)((sqrtf(8.f * tb + 1.f) - 1.f) * 0.5f);
        while ((I + 1) * (I + 2) / 2 <= tb) I++;
        while (I * (I + 1) / 2 > tb) I--;
        int K = tb - I * (I + 1) / 2;
        int gi = m0 + I * 4, gk = m0 + K * 4;
        float acc[4][4] = {{0.f}};
#pragma unroll
        for (int u = 0; u < 16; u++) {
          int jj = (u + t) & 15;         // lane-rotated to spread banks
          float ai[4], ak[4];
#pragma unroll
          for (int m = 0; m < 4; m++) ai[m] = a[AIDX(gi + m, j0 + jj)];
#pragma unroll
          for (int n = 0; n < 4; n++) ak[n] = a[AIDX(gk + n, j0 + jj)];
#pragma unroll
          for (int m = 0; m < 4; m++)
#pragma unroll
            for (int n = 0; n < 4; n++) acc[m][n] += ai[m] * ak[n];
        }
#pragma unroll
        for (int m = 0; m < 4; m++)
#pragma unroll
          for (int n = 0; n < 4; n++)
            a[AIDX(gi + m, gk + n)] -= acc[m][n];
      }
    }
    __syncthreads();
  }
  for (int idx = t; idx < 16384; idx += 256) {
    int i = idx >> 7, j = idx & 127;
    sig[(size_t)(base + i) * 1024 + base + j] = a[AIDX(i, j)];
  }
}

// trsm: X L^T = A for 64 rows per block. L strict-lower packed in LDS (broadcast reads),
// X transposed in LDS with rotation swizzle. Panel-blocked: rank-j0 register update +
// single-wave 16x16 solve. Diag reciprocals in wave-0 registers via shfl.
#define XIDX(j, r) (((j) << 6) + (((r) + (j)) & 63))
__global__ __launch_bounds__(256) void k_chol_trsm(float* __restrict__ sig, int p) {
  __shared__ float Ls[8128];     // strict lower: sl(k,j) = k*(k-1)/2 + j
  __shared__ float XT[8192];     // XT[j][r] swizzled, pitch 64
  int t = threadIdx.x;
  int base = p * 128;
  int row0 = base + 128 + blockIdx.x * 64;
  int r = t & 63, wv = t >> 6;
  for (int idx = t; idx < 8128; idx += 256) {
    int k = (int)((sqrtf(8.f * idx + 1.f) + 1.f) * 0.5f);
    while (k * (k - 1) / 2 > idx) k--;
    while ((k + 1) * k / 2 <= idx) k++;
    int j = idx - k * (k - 1) / 2;
    Ls[idx] = sig[(size_t)(base + k) * 1024 + base + j];
  }
  for (int idx = t; idx < 8192; idx += 256) {
    int rr = idx >> 7, j = idx & 127;
    XT[XIDX(j, rr)] = sig[(size_t)(row0 + rr) * 1024 + base + j];
  }
  float rd0 = 0.f, rd1 = 0.f;
  if (wv == 0) {
    rd0 = 1.0f / sig[(size_t)(base + r) * 1024 + base + r];
    rd1 = 1.0f / sig[(size_t)(base + 64 + r) * 1024 + base + 64 + r];
  }
  __syncthreads();
  for (int pb = 0; pb < 8; pb++) {
    int j0 = pb * 16;
    if (j0 > 0) {
      int c0 = j0 + wv * 4;
      int b0 = c0 * (c0 - 1) / 2, b1 = (c0 + 1) * c0 / 2;
      int b2 = (c0 + 2) * (c0 + 1) / 2, b3 = (c0 + 3) * (c0 + 2) / 2;
      float acc0 = 0.f, acc1 = 0.f, acc2 = 0.f, acc3 = 0.f;
      for (int k = 0; k < j0; k++) {
        float xk = XT[XIDX(k, r)];
        acc0 += xk * Ls[b0 + k];
        acc1 += xk * Ls[b1 + k];
        acc2 += xk * Ls[b2 + k];
        acc3 += xk * Ls[b3 + k];
      }
      XT[XIDX(c0 + 0, r)] -= acc0;
      XT[XIDX(c0 + 1, r)] -= acc1;
      XT[XIDX(c0 + 2, r)] -= acc2;
      XT[XIDX(c0 + 3, r)] -= acc3;
    }
    __syncthreads();
    if (wv == 0) {
#pragma unroll
      for (int jj = 0; jj < 16; jj++) {
        int j = j0 + jj;
        float rdj = (j < 64) ? __shfl(rd0, j & 63) : __shfl(rd1, j & 63);
        float xj = XT[XIDX(j, r)] * rdj;
        XT[XIDX(j, r)] = xj;
#pragma unroll
        for (int kk = jj + 1; kk < 16; kk++) {
          int k2 = j0 + kk;
          XT[XIDX(k2, r)] -= xj * Ls[k2 * (k2 - 1) / 2 + j];
        }
      }
    }
    __syncthreads();
  }
  for (int idx = t; idx < 8192; idx += 256) {
    int rr = idx >> 7, j = idx & 127;
    sig[(size_t)(row0 + rr) * 1024 + base + j] = XT[XIDX(j, rr)];
  }
}

__global__ __launch_bounds__(256) void k_chol_syrk(float* __restrict__ sig, int p) {
  __shared__ float PA[64][65], PB[64][65];
  int t = threadIdx.x;
  int tb = p * 128 + 128;
  int bx = blockIdx.x;
  int I = 0;
  while ((I + 1) * (I + 2) / 2 <= bx) I++;
  int K = bx - I * (I + 1) / 2;
  int gi = tb + I * 64, gk = tb + K * 64;
  int a4 = t >> 4, b4 = t & 15;
  float acc[4][4];
#pragma unroll
  for (int m = 0; m < 4; m++)
#pragma unroll
    for (int n = 0; n < 4; n++) acc[m][n] = 0.f;
  for (int ch = 0; ch < 2; ch++) {
    int cb = p * 128 + ch * 64;
    for (int idx = t; idx < 4096; idx += 256) {
      int rr = idx >> 6, cc = idx & 63;
      PA[rr][cc] = sig[(size_t)(gi + rr) * 1024 + cb + cc];
      PB[rr][cc] = sig[(size_t)(gk + rr) * 1024 + cb + cc];
    }
    __syncthreads();
    for (int j = 0; j < 64; j++) {
      float pa[4], pb[4];
#pragma unroll
      for (int m = 0; m < 4; m++) pa[m] = PA[a4 * 4 + m][j];
#pragma unroll
      for (int n = 0; n < 4; n++) pb[n] = PB[b4 * 4 + n][j];
#pragma unroll
      for (int m = 0; m < 4; m++)
#pragma unroll
        for (int n = 0; n < 4; n++) acc[m][n] += pa[m] * pb[n];
    }
    __syncthreads();
  }
#pragma unroll
  for (int m = 0; m < 4; m++)
#pragma unroll
    for (int n = 0; n < 4; n++)
      sig[(size_t)(gi + a4 * 4 + m) * 1024 + gk + b4 * 4 + n] -= acc[m][n];
}

// ---------------- VOS: gather eps_sel, vos = mu + eps_sel L^T, scores_vos, energy ----------------
__global__ __launch_bounds__(256) void k_vos(const float* __restrict__ eps,
                                             const float* __restrict__ L,
                                             const float* __restrict__ mu,
                                             const float* __restrict__ Wp,
                                             const float* __restrict__ bp,
                                             const float* __restrict__ we,
                                             const unsigned long long* __restrict__ amax,
                                             float* __restrict__ E) {
  __shared__ float es[1024];
  __shared__ float ys[1024];
  __shared__ float sv[16];
  int c = blockIdx.x, t = threadIdx.x;
  int idx = (int)(amax[c] & 0xffffffffULL);
  for (int i = t; i < 1024; i += 256) es[i] = eps[((size_t)c * S_ + idx) * R_ + i];
  __syncthreads();
  for (int rep = 0; rep < 4; rep++) {
    int i = rep * 256 + t;
    const float* Lr = L + (size_t)i * 1024;
    float a0 = 0.f, a1 = 0.f, a2 = 0.f, a3 = 0.f;
    int j = 0;
    for (; j + 3 <= i; j += 4) {
      a0 += es[j] * Lr[j];
      a1 += es[j + 1] * Lr[j + 1];
      a2 += es[j + 2] * Lr[j + 2];
      a3 += es[j + 3] * Lr[j + 3];
    }
    for (; j <= i; j++) a0 += es[j] * Lr[j];
    ys[i] = mu[c * R_ + i] * 1e-3f + ((a0 + a1) + (a2 + a3));
  }
  __syncthreads();
  if (t < C_) {
    float acc = bp[t];
    const float* Wr = Wp + (size_t)t * R_;
    for (int j = 0; j < 1024; j++) acc += ys[j] * Wr[j];
    sv[t] = acc;
  }
  __syncthreads();
  if (t == 0) {
    float m = -1e30f;
    for (int k = 0; k < C_; k++) m = fmaxf(m, sv[k]);
    float sum = 0.f;
    for (int k = 0; k < C_; k++) sum += expf(sv[k] - m) * fmaxf(we[k], 0.f);
    E[N_ + c] = m + logf(sum);
  }
}

// ---------------- tail MLP + BCE + outputs ----------------
__global__ __launch_bounds__(256) void k_dist(const float* __restrict__ E,
                                              const float* __restrict__ W1,
                                              const float* __restrict__ b1,
                                              const float* __restrict__ W2,
                                              const float* __restrict__ b2,
                                              const float* __restrict__ cls_accum,
                                              float* __restrict__ out) {
  __shared__ float sW1[512], sb1[512], sW2[512];
  __shared__ float red[4];
  int t = threadIdx.x;
  for (int i = t; i < 512; i += 256) { sW1[i] = W1[i]; sb1[i] = b1[i]; sW2[i] = W2[i]; }
  __syncthreads();
  float sum = 0.f;
  for (int i = t; i < N_ + C_; i += 256) {
    float e = E[i];
    float acc = b2[0];
    for (int j = 0; j < 512; j++) acc += sW2[j] * fmaxf(e * sW1[j] + sb1[j], 0.f);
    float y = (i < N_) ? 1.f : 0.f;
    float l = fmaxf(acc, 0.f) - acc * y + log1pf(expf(-fabsf(acc)));
    sum += l;
  }
#pragma unroll
  for (int d = 32; d > 0; d >>= 1) sum += __shfl_xor(sum, d);
  if ((t & 63) == 0) red[t >> 6] = sum;
  __syncthreads();
  if (t == 0) {
    out[1] = 0.1f * (red[0] + red[1] + red[2] + red[3]) / 522.f;
    out[0] = *cls_accum / 512.f;
  }
}

extern "C" void kernel_launch(void* const* d_in, const int* in_sizes, int n_in,
                              void* d_out, int out_size, void* d_ws, size_t ws_size,
                              hipStream_t stream) {
  (void)in_sizes; (void)n_in; (void)out_size; (void)ws_size;
  const float* box  = (const float*)d_in[0];
  const int*   lab  = (const int*)d_in[1];
  const float* idd  = (const float*)d_in[2];
  const float* Wp   = (const float*)d_in[4];
  const float* bp   = (const float*)d_in[5];
  const float* we   = (const float*)d_in[6];
  const float* W1   = (const float*)d_in[7];
  const float* b1   = (const float*)d_in[8];
  const float* W2   = (const float*)d_in[9];
  const float* b2   = (const float*)d_in[10];
  const float* eps  = (const float*)d_in[11];
  float* out = (float*)d_out;

  char* ws = (char*)d_ws;
  uint16_t* Dt = (uint16_t*)(ws + OFF_DT);
  float* GP    = (float*)(ws + OFF_GP);
  float* sig   = (float*)(ws + OFF_SIG);
  float* mu    = (float*)(ws + OFF_MU);
  float* E     = (float*)(ws + OFF_E);
  float* clsa  = (float*)(ws + OFF_CLS);
  unsigned long long* amax = (unsigned long long*)(ws + OFF_AMAX);
  int* kc   = (int*)(ws + OFF_KC);
  int* goff = (int*)(ws + OFF_GOFF);
  int* gidx = (int*)(ws + OFF_GIDX);

  hipLaunchKernelGGL(k_prep, dim3(1), dim3(256), 0, stream, lab, kc, goff, gidx, mu, clsa, amax);
  hipLaunchKernelGGL(k_epsmax, dim3(127, C_), dim3(256), 0, stream, eps, amax);
  hipLaunchKernelGGL(k_scores, dim3(N_), dim3(64), 0, stream, box, lab, Wp, bp, we, E, clsa);
  hipLaunchKernelGGL(k_convert, dim3(160, 16), dim3(256), 0, stream, idd, box, kc, goff, gidx, Dt, mu);
  hipLaunchKernelGGL(k_gemm, dim3(8, 8, 4), dim3(256), 0, stream, Dt, GP);
  hipLaunchKernelGGL(k_reduce, dim3(4096), dim3(256), 0, stream, GP, mu, sig);
  for (int p = 0; p < 8; p++) {
    hipLaunchKernelGGL(k_chol_diag, dim3(1), dim3(256), 0, stream, sig, p);
    int rows = 1024 - 128 * (p + 1);
    if (rows > 0) {
      int nb = rows / 64;
      hipLaunchKernelGGL(k_chol_trsm, dim3(nb), dim3(256), 0, stream, sig, p);
      hipLaunchKernelGGL(k_chol_syrk, dim3(nb * (nb + 1) / 2), dim3(256), 0, stream, sig, p);
    }
  }
  hipLaunchKernelGGL(k_vos, dim3(C_), dim3(256), 0, stream, eps, sig, mu, Wp, bp, we, amax, E);
  hipLaunchKernelGGL(k_dist, dim3(1), dim3(256), 0, stream, E, W1, b1, W2, b2, clsa, out);
}